// Round 8
// baseline (73.784 us; speedup 1.0000x reference)
//
#include <hip/hip_runtime.h>

typedef __attribute__((ext_vector_type(8))) _Float16 half8;
typedef __attribute__((ext_vector_type(4))) _Float16 half4v;
typedef __attribute__((ext_vector_type(4))) float f32x4;
typedef float f32x4u __attribute__((ext_vector_type(4), aligned(4)));
typedef float f32x2u __attribute__((ext_vector_type(2), aligned(4)));

#define EPSF 1e-6f

__device__ __forceinline__ void glds16(const void* g, void* l) {
    __builtin_amdgcn_global_load_lds(
        (const __attribute__((address_space(1))) unsigned*)g,
        (__attribute__((address_space(3))) unsigned*)l, 16, 0, 0);
}
__device__ __forceinline__ unsigned short h2u(_Float16 h) {
    union { _Float16 h; unsigned short u; } c; c.h = h; return c.u;
}

// ---------------------------------------------------------------------------
// prep: Mh[f][768] = fp16 of stacked [A|Bw|Cw] (K-contig); Wh[g][256] = fp16(W).
// ---------------------------------------------------------------------------
__global__ __launch_bounds__(256) void prep_kernel(
    const float* __restrict__ A, const float* __restrict__ Bw,
    const float* __restrict__ Cw, const float* __restrict__ W,
    _Float16* __restrict__ Mh, _Float16* __restrict__ Wh)
{
    int f = blockIdx.x, e = threadIdx.x;
    Mh[f * 768 + e]       = (_Float16)A[f * 256 + e];
    Mh[f * 768 + 256 + e] = (_Float16)Bw[f * 256 + e];
    Mh[f * 768 + 512 + e] = (_Float16)Cw[f * 256 + e];
    Wh[f * 256 + e]       = (_Float16)W[f * 256 + e];
}

// ---------------------------------------------------------------------------
// fused1 v4: full double-buffer, ONE __syncthreads per e-block.
// Per eb: { stageA(eb+1)->A[nxt] ; computeT(eb+1)->T[nxt] ; loadXJ(eb+2) ;
//           MFMA on A[cur],T[cur] ; barrier }.
// Every async op drained at the barrier was issued a full phase earlier ->
// no exposed latency.  Double buffers make the single barrier race-free.
// LDS: A 2x48K @0, T 2x22.5K @98304 -> 144384 B -> 1 block/CU, 8 waves.
// Block (b, 32n), wave tile 48c x 64f (2 wc x 4 wf).  grid 512.
// ---------------------------------------------------------------------------
__global__ __launch_bounds__(512, 2) void fused1_kernel(
    const float* __restrict__ X, const float* __restrict__ Jp,
    const _Float16* __restrict__ Mh, _Float16* __restrict__ Y)
{
    extern __shared__ char lds[];
    const int T_OFF = 98304;
    int tid = threadIdx.x;
    int b  = blockIdx.x >> 5;
    int n0 = (blockIdx.x & 31) * 32;

    int l = tid & 63, lr = l & 15, lq = l >> 4;
    int w = tid >> 6, wc = w & 1, wf = w >> 1;
    int nl = tid >> 4, ep = tid & 15;

    size_t pb0 = ((size_t)((b * 1024 + n0 + nl) * 256) + 2 * ep) * 3;

    auto loadXJ = [&](int eb, float* xs, float* js) {
        size_t pb = pb0 + (size_t)eb * 96;
        f32x4u xa = *(const f32x4u*)(X + pb);
        f32x2u xb = *(const f32x2u*)(X + pb + 4);
        f32x4u ja = *(const f32x4u*)(Jp + pb);
        f32x2u jb = *(const f32x2u*)(Jp + pb + 4);
        xs[0]=xa[0]; xs[1]=xa[1]; xs[2]=xa[2]; xs[3]=xa[3]; xs[4]=xb[0]; xs[5]=xb[1];
        js[0]=ja[0]; js[1]=ja[1]; js[2]=ja[2]; js[3]=ja[3]; js[4]=jb[0]; js[5]=jb[1];
    };

    // stage 3 t-slices of M[., eb*32..+32] into A[buf]; 6 glds16/thread.
    auto stageA = [&](int buf, int eb) {
        char* base = lds + buf * 49152;
        #pragma unroll
        for (int h = 0; h < 6; ++h) {
            int m = h * 512 + tid;
            int t = m >> 10, fr = (m >> 2) & 255, slot = m & 3;
            size_t go = ((size_t)fr * 768 + t * 256 + eb * 32
                         + ((slot ^ ((fr >> 1) & 3)) * 8)) * 2;
            glds16((const char*)Mh + go, base + m * 16);
        }
    };

    auto computeT = [&](const float* xs, const float* js, char* tbase) {
        unsigned short hv[2][9];
        #pragma unroll
        for (int p = 0; p < 2; ++p) {
            float x0 = xs[3*p], x1 = xs[3*p+1], x2 = xs[3*p+2];
            float j0 = js[3*p], j1 = js[3*p+1], j2 = js[3*p+2];
            float jj  = j0*j0 + j1*j1 + j2*j2;
            float rn  = __builtin_amdgcn_rcpf(__builtin_amdgcn_sqrtf(jj) + EPSF);
            float nj0 = j0*rn, nj1 = j1*rn, nj2 = j2*rn;
            float s2  = nj0*nj0 + nj1*nj1;
            float uz  = -s2 * __builtin_amdgcn_rcpf(nj2 + EPSF);
            float ru  = __builtin_amdgcn_rcpf(__builtin_amdgcn_sqrtf(s2 + uz*uz) + EPSF);
            float u0 = nj0*ru, u1 = nj1*ru, u2 = uz*ru;
            float v0 = u1*nj2 - u2*nj1;
            float v1 = u2*nj0 - u0*nj2;
            float v2 = u0*nj1 - u1*nj0;
            float r0 = u0*x0 + v0*x1 + nj0*x2;
            float r1 = u1*x0 + v1*x1 + nj1*x2;
            float r2 = u2*x0 + v2*x1 + nj2*x2;
            hv[p][0] = h2u((_Float16)(u0*r0 + u1*r1));
            hv[p][1] = h2u((_Float16)(v0*r0 + v1*r1));
            hv[p][2] = h2u((_Float16)(nj0*r0 + nj1*r1));
            hv[p][3] = h2u((_Float16)(u1*r0 - u0*r1));
            hv[p][4] = h2u((_Float16)(v1*r0 - v0*r1));
            hv[p][5] = h2u((_Float16)(nj1*r0 - nj0*r1));
            hv[p][6] = h2u((_Float16)(u2*r2));
            hv[p][7] = h2u((_Float16)(v2*r2));
            hv[p][8] = h2u((_Float16)(nj2*r2));
        }
        #pragma unroll
        for (int s = 0; s < 9; ++s) {
            int t = s / 3, i = s % 3;
            unsigned pk = (unsigned)hv[0][s] | ((unsigned)hv[1][s] << 16);
            *(unsigned*)(tbase + (t * 96 + i * 32 + nl) * 80 + ep * 4) = pk;
        }
    };

    f32x4 acc[3][4] = {};
    float xs[6], js[6];

    // prologue: A[0], T[0] filled; XJ(1) in regs
    loadXJ(0, xs, js);
    stageA(0, 0);
    computeT(xs, js, lds + T_OFF);
    loadXJ(1, xs, js);
    __syncthreads();

    for (int eb = 0; eb < 8; ++eb) {
        int cur = eb & 1, nxt = cur ^ 1;
        if (eb < 7) {
            stageA(nxt, eb + 1);                     // async, drains at barrier
            computeT(xs, js, lds + T_OFF + nxt * 23040);
        }
        if (eb < 6) loadXJ(eb + 2, xs, js);          // HBM, drains at barrier

        const char* Ab = lds + cur * 49152;
        const char* Tb = lds + T_OFF + cur * 23040;
        #pragma unroll
        for (int t = 0; t < 3; ++t) {
            half8 af[4], bf[3];
            #pragma unroll
            for (int mi = 0; mi < 4; ++mi) {
                int f = wf * 64 + mi * 16 + lr;
                af[mi] = *(const half8*)(Ab + t * 16384 + f * 64
                                         + ((lq ^ ((f >> 1) & 3)) * 16));
            }
            #pragma unroll
            for (int bi = 0; bi < 3; ++bi) {
                int cr = wc * 48 + bi * 16 + lr;
                bf[bi] = *(const half8*)(Tb + (t * 96 + cr) * 80 + lq * 16);
            }
            #pragma unroll
            for (int bi = 0; bi < 3; ++bi)
                #pragma unroll
                for (int mi = 0; mi < 4; ++mi)
                    acc[bi][mi] = __builtin_amdgcn_mfma_f32_16x16x32_f16(af[mi], bf[bi], acc[bi][mi], 0, 0, 0);
        }
        if (eb < 7) __syncthreads();
    }

    // epilogue: D row=f (lq*4+reg), col=c (lr) -> Y[c][f] fp16
    #pragma unroll
    for (int bi = 0; bi < 3; ++bi) {
        int cr = wc * 48 + bi * 16 + lr;
        int i = cr >> 5, nl2 = cr & 31;
        size_t rowb = ((size_t)b * 3072 + i * 1024 + n0 + nl2) * 256;
        #pragma unroll
        for (int mi = 0; mi < 4; ++mi) {
            int fb = wf * 64 + mi * 16 + lq * 4;
            f32x4 v = acc[bi][mi];
            half4v p;
            p.x = (_Float16)v[0]; p.y = (_Float16)v[1];
            p.z = (_Float16)v[2]; p.w = (_Float16)v[3];
            *(half4v*)(Y + rowb + fb) = p;
        }
    }
}

// ---------------------------------------------------------------------------
// gemm2: per b, D[c][g] = sum_f Y[c][f] * W[g][f], single-pass fp16; epilogue
// = VN leaky relu in f32.  Block tile 192c (3i x 64n) x 64g, 4 waves,
// K=256, BK=64 -> 4 kt.  grid: 16*64.  (At its 75-MB memory roofline.)
// ---------------------------------------------------------------------------
__global__ __launch_bounds__(256) void gemm2_kernel(
    const _Float16* __restrict__ Wh, const _Float16* __restrict__ Y,
    float* __restrict__ out, int b_off)
{
    __shared__ char lds[65536];
    int tid = threadIdx.x;
    int bid = blockIdx.x;
    int b   = bid / 64;
    int rt  = bid % 64;
    int g0  = (rt >> 4) * 64;
    int n0  = (rt & 15) * 64;
    size_t bC = (size_t)b * 3072;

    auto stage = [&](int buf, int kt) {
        char* la = lds + buf * 32768;   // A = Y tile: 192 rows x 128 B = 24 KB
        char* lb = la + 24576;          // B = W tile:  64 rows x 128 B =  8 KB
        int k0 = kt * 64;
        int wv = (tid >> 6) * 1024;
        #pragma unroll
        for (int h = 0; h < 6; ++h) {
            int m = h * 256 + tid;
            int row = m >> 3, slot = m & 7;
            int cg = (row >> 6) * 1024 + n0 + (row & 63);
            unsigned sw = (slot * 16) ^ ((row & 7) << 4);
            size_t go = ((bC + cg) * 256 + k0) * 2 + sw;
            glds16((const char*)Y + go, la + h * 4096 + wv);
        }
        #pragma unroll
        for (int h = 0; h < 2; ++h) {
            int m = h * 256 + tid;
            int row = m >> 3, slot = m & 7;
            unsigned sw = (slot * 16) ^ ((row & 7) << 4);
            size_t go = ((size_t)(g0 + row) * 256 + k0) * 2 + sw;
            glds16((const char*)Wh + go, lb + h * 4096 + wv);
        }
    };

    int l = tid & 63, lr = l & 15, lq = l >> 4;
    int w = tid >> 6, wn = w & 1, wg = w >> 1;

    f32x4 acc[3][2][2] = {};
    stage(0, 0);
    __syncthreads();

    for (int kt = 0; kt < 4; ++kt) {
        int cur = kt & 1;
        if (kt < 3) stage(cur ^ 1, kt + 1);
        const char* la = lds + cur * 32768;
        const char* lb = la + 24576;
        #pragma unroll
        for (int kk = 0; kk < 2; ++kk) {
            half8 af[3][2], bg[2];
            #pragma unroll
            for (int i = 0; i < 3; ++i)
                #pragma unroll
                for (int nc = 0; nc < 2; ++nc) {
                    int R = i * 64 + wn * 32 + nc * 16 + lr;
                    af[i][nc] = *(const half8*)(la + R * 128 + (((kk * 4 + lq) * 16) ^ ((R & 7) << 4)));
                }
            #pragma unroll
            for (int gf = 0; gf < 2; ++gf) {
                int R = wg * 32 + gf * 16 + lr;
                bg[gf] = *(const half8*)(lb + R * 128 + (((kk * 4 + lq) * 16) ^ ((R & 7) << 4)));
            }
            #pragma unroll
            for (int i = 0; i < 3; ++i)
                #pragma unroll
                for (int nc = 0; nc < 2; ++nc)
                    #pragma unroll
                    for (int gf = 0; gf < 2; ++gf)
                        acc[i][nc][gf] = __builtin_amdgcn_mfma_f32_16x16x32_f16(af[i][nc], bg[gf], acc[i][nc][gf], 0, 0, 0);
        }
        __syncthreads();
    }

    int b_g = b_off + b;
    #pragma unroll
    for (int nc = 0; nc < 2; ++nc)
        #pragma unroll
        for (int gf = 0; gf < 2; ++gf) {
            int g  = g0 + wg * 32 + gf * 16 + lr;
            int nb = n0 + wn * 32 + nc * 16 + lq * 4;
            float x[3][4];
            #pragma unroll
            for (int i = 0; i < 3; ++i)
                #pragma unroll
                for (int r = 0; r < 4; ++r)
                    x[i][r] = (float)Y[(bC + i * 1024 + nb + r) * 256 + g];
            f32x4 o[3];
            #pragma unroll
            for (int r = 0; r < 4; ++r) {
                float d0 = acc[0][nc][gf][r], d1 = acc[1][nc][gf][r], d2 = acc[2][nc][gf][r];
                float dot = x[0][r] * d0 + x[1][r] * d1 + x[2][r] * d2;
                float dn  = d0 * d0 + d1 * d1 + d2 * d2;
                float sc  = dot / (dn + EPSF);
                bool pos  = dot >= 0.0f;
                float l0 = pos ? x[0][r] : fmaf(-sc, d0, x[0][r]);
                float l1 = pos ? x[1][r] : fmaf(-sc, d1, x[1][r]);
                float l2 = pos ? x[2][r] : fmaf(-sc, d2, x[2][r]);
                o[0][r] = fmaf(0.8f, l0, 0.2f * x[0][r]);
                o[1][r] = fmaf(0.8f, l1, 0.2f * x[1][r]);
                o[2][r] = fmaf(0.8f, l2, 0.2f * x[2][r]);
            }
            #pragma unroll
            for (int i = 0; i < 3; ++i)
                *(f32x4*)(out + ((size_t)(b_g * 256 + g) * 3 + i) * 1024 + nb) = o[i];
        }
}

extern "C" void kernel_launch(void* const* d_in, const int* in_sizes, int n_in,
                              void* d_out, int out_size, void* d_ws, size_t ws_size,
                              hipStream_t stream)
{
    const float* X  = (const float*)d_in[0];
    const float* J  = (const float*)d_in[1];
    const float* A  = (const float*)d_in[2];
    const float* Bw = (const float*)d_in[3];
    const float* Cw = (const float*)d_in[4];
    const float* W  = (const float*)d_in[5];
    float* out = (float*)d_out;

    char* ws = (char*)d_ws;
    _Float16* Mh = (_Float16*)ws;                       // 256*768*2 = 393216
    _Float16* Wh = (_Float16*)(ws + 393216);            // 256*256*2 = 131072
    _Float16* Y  = (_Float16*)(ws + 524288);            // 16*3072*256*2 = 25.2 MB

    // allow 141 KB dynamic LDS (idempotent; not a stream op)
    (void)hipFuncSetAttribute((const void*)fused1_kernel,
                              hipFuncAttributeMaxDynamicSharedMemorySize, 144384);

    hipLaunchKernelGGL(prep_kernel,   dim3(256),  dim3(256), 0, stream,
                       A, Bw, Cw, W, Mh, Wh);
    hipLaunchKernelGGL(fused1_kernel, dim3(512),  dim3(512), 144384, stream,
                       X, J, Mh, Y);
    hipLaunchKernelGGL(gemm2_kernel,  dim3(1024), dim3(256), 0, stream,
                       Wh, Y, out, 0);
}

// Round 9
// 58.562 us; speedup vs baseline: 1.2599x; 1.2599x over previous
//
#include <hip/hip_runtime.h>

typedef __attribute__((ext_vector_type(8))) _Float16 half8;
typedef __attribute__((ext_vector_type(4))) _Float16 half4v;
typedef __attribute__((ext_vector_type(4))) float f32x4;
typedef float f32x4u __attribute__((ext_vector_type(4), aligned(4)));
typedef float f32x2u __attribute__((ext_vector_type(2), aligned(4)));

#define EPSF 1e-6f

__device__ __forceinline__ void glds16(const void* g, void* l) {
    __builtin_amdgcn_global_load_lds(
        (const __attribute__((address_space(1))) unsigned*)g,
        (__attribute__((address_space(3))) unsigned*)l, 16, 0, 0);
}
__device__ __forceinline__ unsigned short h2u(_Float16 h) {
    union { _Float16 h; unsigned short u; } c; c.h = h; return c.u;
}

// ---------------------------------------------------------------------------
// prep: Mh[f][768] = fp16 of stacked [A|Bw|Cw] (K-contig); Wh[g][256] = fp16(W).
// ---------------------------------------------------------------------------
__global__ __launch_bounds__(256) void prep_kernel(
    const float* __restrict__ A, const float* __restrict__ Bw,
    const float* __restrict__ Cw, const float* __restrict__ W,
    _Float16* __restrict__ Mh, _Float16* __restrict__ Wh)
{
    int f = blockIdx.x, e = threadIdx.x;
    Mh[f * 768 + e]       = (_Float16)A[f * 256 + e];
    Mh[f * 768 + 256 + e] = (_Float16)Bw[f * 256 + e];
    Mh[f * 768 + 512 + e] = (_Float16)Cw[f * 256 + e];
    Wh[f * 256 + e]       = (_Float16)W[f * 256 + e];
}

// ---------------------------------------------------------------------------
// fused v5: basis+terms + GEMM1 (part1, = r7 structure) + GEMM2 + VN epilogue
// (part2, in-block: the block owns all 256 f of its 96 c-rows).
// part1: per eb {B1; stageA(48K glds16); computeT->T; B2; 3t x (4af+3bf+12MFMA)}
// part2: Y tile -> LDS (96 rows x 512 B, XOR swz (c&7)<<4); waves re-tile to
//        (nh x gw); K=256 loop: 3 Y-frags (LDS) x 4 W-frags (global->reg,
//        depth-1 prefetch, L2-hot) -> 12 MFMA; mfma(Y,W) puts d0,d1,d2 of one
//        (g,n) in the SAME lane; x from Y_lds; f32x4 stores.
// LDS dyn: A 49152 + T 23040 = 72192 -> 2 blocks/CU.  grid 512 x 512 thr.
// ---------------------------------------------------------------------------
__global__ __launch_bounds__(512, 4) void fused_kernel(
    const float* __restrict__ X, const float* __restrict__ Jp,
    const _Float16* __restrict__ Mh, const _Float16* __restrict__ Wh,
    float* __restrict__ out)
{
    extern __shared__ char lds[];
    const int T_OFF = 49152;
    int tid = threadIdx.x;
    int b  = blockIdx.x >> 5;
    int n0 = (blockIdx.x & 31) * 32;

    int l = tid & 63, lr = l & 15, lq = l >> 4;
    int w = tid >> 6, wc = w & 1, wf = w >> 1;
    int nl = tid >> 4, ep = tid & 15;

    size_t pb0 = ((size_t)((b * 1024 + n0 + nl) * 256) + 2 * ep) * 3;

    auto loadXJ = [&](int eb, float* xs, float* js) {
        size_t pb = pb0 + (size_t)eb * 96;
        f32x4u xa = *(const f32x4u*)(X + pb);
        f32x2u xb = *(const f32x2u*)(X + pb + 4);
        f32x4u ja = *(const f32x4u*)(Jp + pb);
        f32x2u jb = *(const f32x2u*)(Jp + pb + 4);
        xs[0]=xa[0]; xs[1]=xa[1]; xs[2]=xa[2]; xs[3]=xa[3]; xs[4]=xb[0]; xs[5]=xb[1];
        js[0]=ja[0]; js[1]=ja[1]; js[2]=ja[2]; js[3]=ja[3]; js[4]=jb[0]; js[5]=jb[1];
    };

    auto stageA = [&](int eb) {
        #pragma unroll
        for (int h = 0; h < 6; ++h) {
            int m = h * 512 + tid;
            int t = m >> 10, fr = (m >> 2) & 255, slot = m & 3;
            size_t go = ((size_t)fr * 768 + t * 256 + eb * 32
                         + ((slot ^ ((fr >> 1) & 3)) * 8)) * 2;
            glds16((const char*)Mh + go, lds + m * 16);
        }
    };

    auto computeT = [&](const float* xs, const float* js) {
        unsigned short hv[2][9];
        #pragma unroll
        for (int p = 0; p < 2; ++p) {
            float x0 = xs[3*p], x1 = xs[3*p+1], x2 = xs[3*p+2];
            float j0 = js[3*p], j1 = js[3*p+1], j2 = js[3*p+2];
            float jj  = j0*j0 + j1*j1 + j2*j2;
            float rn  = __builtin_amdgcn_rcpf(__builtin_amdgcn_sqrtf(jj) + EPSF);
            float nj0 = j0*rn, nj1 = j1*rn, nj2 = j2*rn;
            float s2  = nj0*nj0 + nj1*nj1;
            float uz  = -s2 * __builtin_amdgcn_rcpf(nj2 + EPSF);
            float ru  = __builtin_amdgcn_rcpf(__builtin_amdgcn_sqrtf(s2 + uz*uz) + EPSF);
            float u0 = nj0*ru, u1 = nj1*ru, u2 = uz*ru;
            float v0 = u1*nj2 - u2*nj1;
            float v1 = u2*nj0 - u0*nj2;
            float v2 = u0*nj1 - u1*nj0;
            float r0 = u0*x0 + v0*x1 + nj0*x2;
            float r1 = u1*x0 + v1*x1 + nj1*x2;
            float r2 = u2*x0 + v2*x1 + nj2*x2;
            hv[p][0] = h2u((_Float16)(u0*r0 + u1*r1));
            hv[p][1] = h2u((_Float16)(v0*r0 + v1*r1));
            hv[p][2] = h2u((_Float16)(nj0*r0 + nj1*r1));
            hv[p][3] = h2u((_Float16)(u1*r0 - u0*r1));
            hv[p][4] = h2u((_Float16)(v1*r0 - v0*r1));
            hv[p][5] = h2u((_Float16)(nj1*r0 - nj0*r1));
            hv[p][6] = h2u((_Float16)(u2*r2));
            hv[p][7] = h2u((_Float16)(v2*r2));
            hv[p][8] = h2u((_Float16)(nj2*r2));
        }
        #pragma unroll
        for (int s = 0; s < 9; ++s) {
            int t = s / 3, i = s % 3;
            unsigned pk = (unsigned)hv[0][s] | ((unsigned)hv[1][s] << 16);
            *(unsigned*)(lds + T_OFF + (t * 96 + i * 32 + nl) * 80 + ep * 4) = pk;
        }
    };

    // ---------------- part 1: GEMM1 (r7 structure, verbatim) ----------------
    f32x4 acc[3][4] = {};
    float xs[6], js[6];
    loadXJ(0, xs, js);

    for (int eb = 0; eb < 8; ++eb) {
        __syncthreads();                 // B1: all reads of A/T (eb-1) done
        stageA(eb);                      // async -> A region
        computeT(xs, js);                // VALU hides stage latency
        __syncthreads();                 // B2: A + T visible
        if (eb < 7) loadXJ(eb + 1, xs, js);

        #pragma unroll
        for (int t = 0; t < 3; ++t) {
            half8 af[4], bf[3];
            #pragma unroll
            for (int mi = 0; mi < 4; ++mi) {
                int f = wf * 64 + mi * 16 + lr;
                af[mi] = *(const half8*)(lds + t * 16384 + f * 64
                                         + ((lq ^ ((f >> 1) & 3)) * 16));
            }
            #pragma unroll
            for (int bi = 0; bi < 3; ++bi) {
                int cr = wc * 48 + bi * 16 + lr;
                bf[bi] = *(const half8*)(lds + T_OFF + (t * 96 + cr) * 80 + lq * 16);
            }
            #pragma unroll
            for (int bi = 0; bi < 3; ++bi)
                #pragma unroll
                for (int mi = 0; mi < 4; ++mi)
                    acc[bi][mi] = __builtin_amdgcn_mfma_f32_16x16x32_f16(af[mi], bf[bi], acc[bi][mi], 0, 0, 0);
        }
    }

    // ---------------- part 2: Y -> LDS, GEMM2 + VN epilogue ----------------
    __syncthreads();                     // all part1 LDS reads complete
    // Y tile: row c (0..95 = i*32+n), 512-B pitch, byte ^= (c&7)<<4
    #pragma unroll
    for (int bi = 0; bi < 3; ++bi) {
        int c = wc * 48 + bi * 16 + lr;
        #pragma unroll
        for (int mi = 0; mi < 4; ++mi) {
            int fb2 = (wf * 64 + mi * 16 + lq * 4) * 2;
            f32x4 v = acc[bi][mi];
            half4v p;
            p.x = (_Float16)v[0]; p.y = (_Float16)v[1];
            p.z = (_Float16)v[2]; p.w = (_Float16)v[3];
            *(half4v*)(lds + c * 512 + (fb2 ^ ((c & 7) << 4))) = p;
        }
    }

    int nh = w & 1, gw = w >> 1;         // wave re-tile: 2 n-halves x 4 g-quarters
    half8 wreg[2][4];
    #pragma unroll
    for (int gf = 0; gf < 4; ++gf) {     // prefetch kt=0 W-frags (L2-hot)
        int g = gw * 64 + gf * 16 + lr;
        wreg[0][gf] = *(const half8*)(Wh + (size_t)g * 256 + lq * 8);
    }
    __syncthreads();                     // Y_lds visible

    f32x4 acc2[3][4] = {};
    #pragma unroll
    for (int kt = 0; kt < 8; ++kt) {
        if (kt < 7) {
            #pragma unroll
            for (int gf = 0; gf < 4; ++gf) {
                int g = gw * 64 + gf * 16 + lr;
                wreg[(kt + 1) & 1][gf] =
                    *(const half8*)(Wh + (size_t)g * 256 + (kt + 1) * 32 + lq * 8);
            }
        }
        half8 yf[3];
        #pragma unroll
        for (int ci = 0; ci < 3; ++ci) {
            int c = ci * 32 + nh * 16 + lr;
            yf[ci] = *(const half8*)(lds + c * 512
                                     + ((kt * 64 + lq * 16) ^ ((c & 7) << 4)));
        }
        #pragma unroll
        for (int ci = 0; ci < 3; ++ci)
            #pragma unroll
            for (int gf = 0; gf < 4; ++gf)
                acc2[ci][gf] = __builtin_amdgcn_mfma_f32_16x16x32_f16(
                    yf[ci], wreg[kt & 1][gf], acc2[ci][gf], 0, 0, 0);
    }

    // epilogue: lane holds d_i = acc2[i][gf][r] for (g = gw*64+gf*16+lr,
    // n = n0+nh*16+lq*4+r); x_i from Y_lds[c=i*32+nh*16+lq*4+r][g].
    #pragma unroll
    for (int gf = 0; gf < 4; ++gf) {
        int g = gw * 64 + gf * 16 + lr;
        f32x4 o[3];
        #pragma unroll
        for (int r = 0; r < 4; ++r) {
            float xv[3];
            #pragma unroll
            for (int ci = 0; ci < 3; ++ci) {
                int c = ci * 32 + nh * 16 + lq * 4 + r;
                xv[ci] = (float)*(const _Float16*)(lds + c * 512
                                 + ((g * 2) ^ ((c & 7) << 4)));
            }
            float d0 = acc2[0][gf][r], d1 = acc2[1][gf][r], d2 = acc2[2][gf][r];
            float dot = xv[0] * d0 + xv[1] * d1 + xv[2] * d2;
            float dn  = d0 * d0 + d1 * d1 + d2 * d2;
            float sc  = dot / (dn + EPSF);
            bool pos  = dot >= 0.0f;
            float l0 = pos ? xv[0] : fmaf(-sc, d0, xv[0]);
            float l1 = pos ? xv[1] : fmaf(-sc, d1, xv[1]);
            float l2 = pos ? xv[2] : fmaf(-sc, d2, xv[2]);
            o[0][r] = fmaf(0.8f, l0, 0.2f * xv[0]);
            o[1][r] = fmaf(0.8f, l1, 0.2f * xv[1]);
            o[2][r] = fmaf(0.8f, l2, 0.2f * xv[2]);
        }
        int nb = n0 + nh * 16 + lq * 4;
        #pragma unroll
        for (int i = 0; i < 3; ++i)
            *(f32x4*)(out + ((size_t)(b * 256 + g) * 3 + i) * 1024 + nb) = o[i];
    }
}

extern "C" void kernel_launch(void* const* d_in, const int* in_sizes, int n_in,
                              void* d_out, int out_size, void* d_ws, size_t ws_size,
                              hipStream_t stream)
{
    const float* X  = (const float*)d_in[0];
    const float* J  = (const float*)d_in[1];
    const float* A  = (const float*)d_in[2];
    const float* Bw = (const float*)d_in[3];
    const float* Cw = (const float*)d_in[4];
    const float* W  = (const float*)d_in[5];
    float* out = (float*)d_out;

    char* ws = (char*)d_ws;
    _Float16* Mh = (_Float16*)ws;                       // 256*768*2 = 393216
    _Float16* Wh = (_Float16*)(ws + 393216);            // 256*256*2 = 131072

    (void)hipFuncSetAttribute((const void*)fused_kernel,
                              hipFuncAttributeMaxDynamicSharedMemorySize, 72192);

    hipLaunchKernelGGL(prep_kernel,  dim3(256), dim3(256), 0, stream,
                       A, Bw, Cw, W, Mh, Wh);
    hipLaunchKernelGGL(fused_kernel, dim3(512), dim3(512), 72192, stream,
                       X, J, Mh, Wh, out);
}